// Round 11
// baseline (484.621 us; speedup 1.0000x reference)
//
#include <hip/hip_runtime.h>
#include <hip/hip_bf16.h>
#include <cstddef>
#include <cstdint>

#define N_NODES 10000
#define N_EDGES 160000
#define BATCH 32
#define IN_FEAT 64
#define POLY_K 5
#define OUT_FEAT 128
#define KTOT 320               // IN_FEAT * POLY_K
#define POOLSZ 4
#define NPOOL 2500
#define NSL 16                 // column slices (slice-contiguous layout)

typedef short bf16x8 __attribute__((ext_vector_type(8)));
typedef unsigned short u16x8 __attribute__((ext_vector_type(8)));
typedef unsigned int u32x4 __attribute__((ext_vector_type(4)));
typedef float f32x4 __attribute__((ext_vector_type(4)));
typedef float f32x2 __attribute__((ext_vector_type(2)));

__device__ __forceinline__ unsigned short f2bf(float f) {
  unsigned int u = __float_as_uint(f);
  unsigned int r = u + 0x7FFFu + ((u >> 16) & 1u);   // RNE
  return (unsigned short)(r >> 16);
}
__device__ __forceinline__ float bf2f(unsigned short u) {
  return __uint_as_float(((unsigned int)u) << 16);
}
// unpack one dword (2 packed bf16) to float2 {lo, hi} — 2 VALU ops
__device__ __forceinline__ f32x2 unpk(unsigned int u) {
  f32x2 r;
  r[0] = __uint_as_float(u << 16);
  r[1] = __uint_as_float(u & 0xFFFF0000u);
  return r;
}

// ---------------- CSR build ----------------

__global__ void zero_int_kernel(int* __restrict__ p, int n) {
  int i = blockIdx.x * 256 + threadIdx.x;
  if (i < n) p[i] = 0;
}

__global__ void hist_kernel(const int* __restrict__ rows, int* __restrict__ deg) {
  int e = blockIdx.x * 256 + threadIdx.x;
  if (e < N_EDGES) atomicAdd(&deg[rows[e]], 1);
}

// wave-shuffle scan: 16 waves x 64 lanes, 4 barriers/chunk
__global__ void scan_kernel(const int* __restrict__ deg, int* __restrict__ row_start,
                            int* __restrict__ cursor) {
  __shared__ int wsum[16];
  __shared__ int carry_sm;
  int t = threadIdx.x;
  int lane = t & 63, wid = t >> 6;
  if (t == 0) { carry_sm = 0; row_start[0] = 0; }
  __syncthreads();
  for (int base = 0; base < N_NODES; base += 1024) {
    int idx = base + t;
    int v = (idx < N_NODES) ? deg[idx] : 0;
    int x = v;
    #pragma unroll
    for (int off = 1; off < 64; off <<= 1) {
      int y = __shfl_up(x, off, 64);
      if (lane >= off) x += y;
    }
    if (lane == 63) wsum[wid] = x;
    __syncthreads();
    if (wid == 0) {
      int sv = (lane < 16) ? wsum[lane] : 0;
      #pragma unroll
      for (int off = 1; off < 16; off <<= 1) {
        int y = __shfl_up(sv, off, 64);
        if (lane >= off) sv += y;
      }
      if (lane < 16) wsum[lane] = sv;
    }
    __syncthreads();
    int incl = x + (wid > 0 ? wsum[wid - 1] : 0) + carry_sm;
    if (idx < N_NODES) {
      row_start[idx + 1] = incl;
      cursor[idx] = incl - v;
    }
    __syncthreads();                 // all carry reads done
    if (t == 1023) carry_sm = incl;  // wid=15,lane=63 -> chunk total (incl carry)
    __syncthreads();
  }
}

// scatter into interleaved {col, val_bits} pairs: one 8-B load per edge in spmm
__global__ void scatter_kernel(const int* __restrict__ rows, const int* __restrict__ cols,
                               const float* __restrict__ vals, int* __restrict__ cursor,
                               int2* __restrict__ csr_pairs) {
  int e = blockIdx.x * 256 + threadIdx.x;
  if (e < N_EDGES) {
    int r = rows[e];
    int p = atomicAdd(&cursor[r], 1);
    csr_pairs[p] = make_int2(cols[e], __float_as_int(vals[e]));
  }
}

// ---------------- weight prepack: B-fragment lane order, k' = kpoly*64+f ----------------

__global__ void wpack_kernel(const float* __restrict__ weight, unsigned short* __restrict__ wpack) {
  int id = blockIdx.x * 256 + threadIdx.x;      // 8*10*64 = 5120 lane-slots
  if (id >= 5120) return;
  int ft = id / 640;
  int c = (id / 64) % 10;
  int l = id % 64;
  int fo = ft * 16 + (l & 15);
  unsigned short v[8];
  #pragma unroll
  for (int j = 0; j < 8; ++j) {
    int k = c * 32 + ((l >> 4)) * 8 + j;
    int row = (k & 63) * POLY_K + (k >> 6);
    v[j] = f2bf(weight[row * OUT_FEAT + fo]);
  }
  ushort4* dst = (ushort4*)&wpack[(size_t)id * 8];
  dst[0] = make_ushort4(v[0], v[1], v[2], v[3]);
  dst[1] = make_ushort4(v[4], v[5], v[6], v[7]);
}

// ---------------- transpose into slice-contiguous layout (node-blocked) ----------------
// 8 nodes/block: per wave (fixed b) reads 8 adjacent nodes x 64 feats = 2 KB CONTIGUOUS.

template <int BB>
__global__ __launch_bounds__(256) void transpose_kernel(const float* __restrict__ x,
                                                        unsigned short* __restrict__ t0, int b0) {
  constexpr int CB = 64 * BB;
  constexpr int SCOLS = CB / NSL;
  constexpr size_t SLICE_SL = (size_t)N_NODES * SCOLS;
  constexpr int NN = 8;                     // nodes per block (grid 1250)
  int n0 = blockIdx.x * NN;
  int t = threadIdx.x;
  int bsub = t >> 6;                        // 0..3
  int n = (t >> 3) & 7;                     // 0..7
  int f8 = t & 7;                           // 0..7 (8 floats each)
  int node = n0 + n;
  #pragma unroll
  for (int bi = 0; bi < BB / 4; ++bi) {
    int b = bi * 4 + bsub;
    const float* xp = &x[((size_t)(b0 + b) * N_NODES + node) * IN_FEAT + f8 * 8];
    float4 v0 = *(const float4*)xp;
    float4 v1 = *(const float4*)(xp + 4);
    u16x8 o;
    o[0] = f2bf(v0.x); o[1] = f2bf(v0.y); o[2] = f2bf(v0.z); o[3] = f2bf(v0.w);
    o[4] = f2bf(v1.x); o[5] = f2bf(v1.y); o[6] = f2bf(v1.z); o[7] = f2bf(v1.w);
    int i = b * 64 + f8 * 8;
    int sl = i / SCOLS;
    int cw = i - sl * SCOLS;
    *(u16x8*)&t0[(size_t)sl * SLICE_SL + (size_t)node * SCOLS + cw] = o;
  }
}

// ---------------- SpMM (bf16): ONE ROW PER WAVE, slice-contiguous, pair-CSR ----------------
// Old layout: 4 rows lockstep per wave (16 lanes/row) -> trip = max-of-4 degrees, only 40K
// waves (5/SIMD) against ~500cy dependent chains. New: 64 lanes x 2 cols = 1 row/wave
// (BB=32) -> 160K waves (4x TLP), trip = own degree (zero divergence), row bounds
// wave-uniform -> readfirstlane lets the pair stream go scalar (off the TA path).
// Per-column fma order unchanged (ascending edge index) -> bit-identical output.

template <int BB>
__global__ __launch_bounds__(256) void spmm_kernel(const unsigned short* __restrict__ xin,
                                                   const unsigned short* __restrict__ prev,
                                                   unsigned short* __restrict__ xout,
                                                   const int* __restrict__ row_start,
                                                   const int2* __restrict__ csr_pairs,
                                                   float alpha, int use_prev) {
  constexpr int CB = 64 * BB;
  constexpr int SCOLS = CB / NSL;       // cols per slice (128 @BB=32)
  constexpr size_t SLICE_SL = (size_t)N_NODES * SCOLS;
  constexpr int LPR = SCOLS / 2;        // lanes per row, 2 cols (1 dword) each
  constexpr int RPW = 64 / LPR;         // rows per wave (1 @BB=32)
  constexpr int RPB = 4 * RPW;          // rows per block (4 waves)
  constexpr int RB = (N_NODES + RPB - 1) / RPB;
  constexpr int PHB = RB * 8;           // blocks per phase
  int bid = blockIdx.x;
  int phase = bid / PHB;
  int rem = bid - phase * PHB;
  int xcd = rem & 7;
  int rowblk = rem >> 3;
  int slice = phase * 8 + xcd;
  int t = threadIdx.x;
  int wid = t >> 6;
  int lane = t & 63;
  int rw = lane / LPR;                  // 0 when RPW==1
  int cl = lane - rw * LPR;
  int n = rowblk * RPB + wid * RPW + rw;
  if (n >= N_NODES) return;
  unsigned off = (unsigned)cl * 2u;

  const unsigned short* xs = xin  + (size_t)slice * SLICE_SL;
  const unsigned short* ps = prev + (size_t)slice * SLICE_SL;
  unsigned short*       os = xout + (size_t)slice * SLICE_SL;

  int s = row_start[n];
  int e = row_start[n + 1];
  if constexpr (RPW == 1) {             // row is wave-uniform: scalarize edge bounds
    s = __builtin_amdgcn_readfirstlane(s);
    e = __builtin_amdgcn_readfirstlane(e);
  }
  f32x2 a = {0.f, 0.f};

  int i = s;
  for (; i + 7 < e; i += 8) {
    int2 E[8];
    #pragma unroll
    for (int u = 0; u < 8; ++u) E[u] = csr_pairs[i + u];
    unsigned d[8];
    #pragma unroll
    for (int u = 0; u < 8; ++u) d[u] = *(const unsigned*)&xs[(unsigned)E[u].x * SCOLS + off];
    #pragma unroll
    for (int u = 0; u < 8; ++u) {
      float vv = __int_as_float(E[u].y);
      f32x2 w = {vv, vv};
      a = __builtin_elementwise_fma(w, unpk(d[u]), a);
    }
  }
  for (; i < e; ++i) {
    int2 E0 = csr_pairs[i];
    unsigned d0 = *(const unsigned*)&xs[(unsigned)E0.x * SCOLS + off];
    float vv = __int_as_float(E0.y);
    f32x2 w0 = {vv, vv};
    a = __builtin_elementwise_fma(w0, unpk(d0), a);
  }

  unsigned nelt = (unsigned)n * SCOLS + off;
  float v0, v1;
  if (use_prev) {
    unsigned qd = *(const unsigned*)&ps[nelt];
    f32x2 q = unpk(qd);
    v0 = alpha * a[0] - q[0];
    v1 = alpha * a[1] - q[1];
  } else {
    v0 = alpha * a[0];
    v1 = alpha * a[1];
  }
  unsigned outw = (unsigned)f2bf(v0) | ((unsigned)f2bf(v1) << 16);
  *(unsigned*)&os[nelt] = outw;
}

// ---------------- MFMA GEMM + bias + ReLU + maxpool(4), 2-phase pipelined staging ----------
// Round-8 config (MB=16, 40960 B LDS, 4 blocks/CU): best-measured total. Phase-1: stage
// kpoly 0-1; barrier; ISSUE stage kpoly 2-4, compute c=0..3 with PRE-LOADED B-fragments
// (pure LDS+MFMA, no VMEM consume); barrier; compute c=4..9.

template <int BB>
__global__ __launch_bounds__(256, 4) void gemm_mfma_kernel(const unsigned short* __restrict__ slices,
                                                           const unsigned short* __restrict__ wpack,
                                                           const float* __restrict__ bias,
                                                           float* __restrict__ out, int b0) {
  constexpr int CB = 64 * BB;
  constexpr int SCOLS = CB / NSL;
  constexpr size_t SLICE_SL = (size_t)N_NODES * SCOLS;
  constexpr int MB = (BB >= 16) ? 16 : BB;        // b's per block
  constexpr int MT = MB / 4;                      // 16-row M-tiles
  constexpr int SPAN = MB * 64;                   // cols per block
  constexpr int ROWS = 4 * MB;                    // A rows (bloc*4 + nd)
  constexpr int CHUNKS = ROWS * 40;               // 16B chunks total
  __shared__ unsigned short A[POLY_K * ROWS * 64]; // K-major: [kpoly][row][64]

  int g = blockIdx.x;
  int bh = blockIdx.y;
  int t = threadIdx.x;

  auto stage = [&](int idx0) {
    int idx = idx0 + t;
    int kpoly = idx / (ROWS * 8);
    int rem = idx - kpoly * (ROWS * 8);
    int row = rem >> 3;
    int cphys = idx & 7;
    int clog3 = cphys ^ (row & 7);                // swizzle within kpoly's 8-chunk group
    int fb = clog3 * 8;
    int bloc = row >> 2;
    int nd = row & 3;
    int c = bh * SPAN + bloc * 64 + fb;           // global column in [0, CB)
    int sl = c / SCOLS;
    int cw = c & (SCOLS - 1);
    const unsigned short* gsrc = &slices[((size_t)kpoly * NSL + sl) * SLICE_SL +
                                         (size_t)(g * POOLSZ + nd) * SCOLS + cw];
    unsigned short* lbase = &A[(size_t)(idx0 + (t & 192)) * 8];   // wave-uniform base
    __builtin_amdgcn_global_load_lds((const __attribute__((address_space(1))) unsigned int*)gsrc,
                                     (__attribute__((address_space(3))) unsigned int*)lbase,
                                     16, 0, 0);
  };

  int w = t >> 6;          // wave 0..3: fo-tiles {2w, 2w+1}
  int l = t & 63;
  int lm = l & 15;
  int q = l >> 4;
  int swz = lm & 7;

  f32x4 acc[MT][2];
  #pragma unroll
  for (int mt = 0; mt < MT; ++mt)
    #pragma unroll
    for (int fj = 0; fj < 2; ++fj) {
      acc[mt][fj][0] = 0.f; acc[mt][fj][1] = 0.f;
      acc[mt][fj][2] = 0.f; acc[mt][fj][3] = 0.f;
    }

  if constexpr (MB == 16) {
    constexpr int PH1 = 2 * ROWS * 8;             // kpoly 0,1 = 1024 chunks = 4 iters
    for (int idx0 = 0; idx0 < PH1; idx0 += 256) stage(idx0);
    // preload B-fragments for c=0..3 (resident after the barrier drain; 32 VGPR)
    bf16x8 bpre[4][2];
    #pragma unroll
    for (int c = 0; c < 4; ++c)
      #pragma unroll
      for (int fj = 0; fj < 2; ++fj)
        bpre[c][fj] = *(const bf16x8*)&wpack[(size_t)((((w * 2 + fj) * 10) + c) * 64 + l) * 8];
    __syncthreads();                              // kpoly 0,1 + bpre resident
    for (int idx0 = PH1; idx0 < CHUNKS; idx0 += 256) stage(idx0);  // kpoly 2..4 in flight
    #pragma unroll
    for (int c = 0; c < 4; ++c) {                 // kpoly 0,1 — pure LDS+MFMA
      #pragma unroll
      for (int mt = 0; mt < MT; ++mt) {
        bf16x8 afrag = *(const bf16x8*)
            &A[((c >> 1) * ROWS + mt * 16 + lm) * 64 + ((((c & 1) * 4 + q) ^ swz) << 3)];
        acc[mt][0] = __builtin_amdgcn_mfma_f32_16x16x32_bf16(afrag, bpre[c][0], acc[mt][0], 0, 0, 0);
        acc[mt][1] = __builtin_amdgcn_mfma_f32_16x16x32_bf16(afrag, bpre[c][1], acc[mt][1], 0, 0, 0);
      }
    }
    __syncthreads();                              // kpoly 2..4 resident
    #pragma unroll
    for (int c = 4; c < 10; ++c) {
      bf16x8 bfrag[2];
      #pragma unroll
      for (int fj = 0; fj < 2; ++fj)
        bfrag[fj] = *(const bf16x8*)&wpack[(size_t)((((w * 2 + fj) * 10) + c) * 64 + l) * 8];
      #pragma unroll
      for (int mt = 0; mt < MT; ++mt) {
        bf16x8 afrag = *(const bf16x8*)
            &A[((c >> 1) * ROWS + mt * 16 + lm) * 64 + ((((c & 1) * 4 + q) ^ swz) << 3)];
        acc[mt][0] = __builtin_amdgcn_mfma_f32_16x16x32_bf16(afrag, bfrag[0], acc[mt][0], 0, 0, 0);
        acc[mt][1] = __builtin_amdgcn_mfma_f32_16x16x32_bf16(afrag, bfrag[1], acc[mt][1], 0, 0, 0);
      }
    }
  } else {
    for (int idx0 = 0; idx0 < CHUNKS; idx0 += 256) stage(idx0);
    __syncthreads();
    #pragma unroll
    for (int c = 0; c < 10; ++c) {
      bf16x8 bfrag[2];
      #pragma unroll
      for (int fj = 0; fj < 2; ++fj)
        bfrag[fj] = *(const bf16x8*)&wpack[(size_t)((((w * 2 + fj) * 10) + c) * 64 + l) * 8];
      #pragma unroll
      for (int mt = 0; mt < MT; ++mt) {
        bf16x8 afrag = *(const bf16x8*)
            &A[((c >> 1) * ROWS + mt * 16 + lm) * 64 + ((((c & 1) * 4 + q) ^ swz) << 3)];
        acc[mt][0] = __builtin_amdgcn_mfma_f32_16x16x32_bf16(afrag, bfrag[0], acc[mt][0], 0, 0, 0);
        acc[mt][1] = __builtin_amdgcn_mfma_f32_16x16x32_bf16(afrag, bfrag[1], acc[mt][1], 0, 0, 0);
      }
    }
  }

  #pragma unroll
  for (int fj = 0; fj < 2; ++fj) {
    int fo = (w * 2 + fj) * 16 + lm;
    float bv = bias[fo];
    #pragma unroll
    for (int mt = 0; mt < MT; ++mt) {
      float mx = fmaxf(fmaxf(acc[mt][fj][0], acc[mt][fj][1]),
                       fmaxf(acc[mt][fj][2], acc[mt][fj][3]));
      float val = fmaxf(mx + bv, 0.f);
      int b = b0 + bh * MB + mt * 4 + q;
      out[((size_t)b * NPOOL + g) * OUT_FEAT + fo] = val;
    }
  }
}

// ---------------- pipeline ----------------

template <int BB>
static void run_pipeline(const float* x, const float* bias,
                         const int* row_start, const int2* csr_pairs,
                         const unsigned short* wpack,
                         unsigned short* slices, float* out, hipStream_t stream) {
  constexpr int CB = 64 * BB;
  constexpr size_t TERM = (size_t)N_NODES * CB;   // elements per k-term (NSL slices)
  constexpr int SCOLS = CB / NSL;
  constexpr int LPR = SCOLS / 2;
  constexpr int RPW = 64 / LPR;
  constexpr int RPB = 4 * RPW;
  constexpr int NBLK = ((N_NODES + RPB - 1) / RPB) * NSL;
  constexpr int MB = (BB >= 16) ? 16 : BB;
  for (int b0 = 0; b0 < BATCH; b0 += BB) {
    transpose_kernel<BB><<<N_NODES / 8, 256, 0, stream>>>(x, slices, b0);
    for (int k = 1; k < POLY_K; ++k) {
      const unsigned short* xin  = slices + (size_t)(k - 1) * TERM;
      const unsigned short* prev = (k >= 2) ? slices + (size_t)(k - 2) * TERM : slices;
      unsigned short* xout = slices + (size_t)k * TERM;
      float alpha = (k == 1) ? 1.0f : 2.0f;
      spmm_kernel<BB><<<NBLK, 256, 0, stream>>>(xin, prev, xout, row_start,
                                                csr_pairs, alpha,
                                                (k >= 2) ? 1 : 0);
    }
    gemm_mfma_kernel<BB><<<dim3(NPOOL, BB / MB), 256, 0, stream>>>(slices, wpack, bias, out, b0);
  }
}

static size_t needed_bytes(int BB) {
  return 1522176u + (size_t)6400000 * BB;   // deg/cursor/row_start/(spare) + pairs + wpack + slices
}

extern "C" void kernel_launch(void* const* d_in, const int* in_sizes, int n_in,
                              void* d_out, int out_size, void* d_ws, size_t ws_size,
                              hipStream_t stream) {
  const float* x        = (const float*)d_in[0];
  const int*   lap_rows = (const int*)d_in[1];
  const int*   lap_cols = (const int*)d_in[2];
  const float* lap_vals = (const float*)d_in[3];
  const float* weight   = (const float*)d_in[4];
  const float* bias     = (const float*)d_in[5];
  float* out = (float*)d_out;

  int* deg       = (int*)d_ws;
  int* cursor    = deg + 10016;
  int* row_start = cursor + 10016;
  int* spare     = row_start + 10016;    // (former perm slot, unused)
  int2* csr_pairs = (int2*)(spare + 10016);
  unsigned short* wpack = (unsigned short*)(csr_pairs + N_EDGES);  // 40960 ushorts
  unsigned short* slices = wpack + 40960;                          // bf16 terms

  int BB = 0;
  if      (ws_size >= needed_bytes(32)) BB = 32;
  else if (ws_size >= needed_bytes(16)) BB = 16;
  else if (ws_size >= needed_bytes(8))  BB = 8;
  else if (ws_size >= needed_bytes(4))  BB = 4;
  if (BB == 0) return;

  zero_int_kernel<<<(N_NODES + 255) / 256, 256, 0, stream>>>(deg, N_NODES);
  hist_kernel<<<(N_EDGES + 255) / 256, 256, 0, stream>>>(lap_rows, deg);
  scan_kernel<<<1, 1024, 0, stream>>>(deg, row_start, cursor);
  scatter_kernel<<<(N_EDGES + 255) / 256, 256, 0, stream>>>(lap_rows, lap_cols, lap_vals,
                                                            cursor, csr_pairs);
  wpack_kernel<<<20, 256, 0, stream>>>(weight, wpack);

  switch (BB) {
    case 32: run_pipeline<32>(x, bias, row_start, csr_pairs, wpack, slices, out, stream); break;
    case 16: run_pipeline<16>(x, bias, row_start, csr_pairs, wpack, slices, out, stream); break;
    case 8:  run_pipeline<8>(x, bias, row_start, csr_pairs, wpack, slices, out, stream); break;
    case 4:  run_pipeline<4>(x, bias, row_start, csr_pairs, wpack, slices, out, stream); break;
  }
}

// Round 12
// 416.625 us; speedup vs baseline: 1.1632x; 1.1632x over previous
//
#include <hip/hip_runtime.h>
#include <hip/hip_bf16.h>
#include <cstddef>
#include <cstdint>

#define N_NODES 10000
#define N_EDGES 160000
#define BATCH 32
#define IN_FEAT 64
#define POLY_K 5
#define OUT_FEAT 128
#define KTOT 320               // IN_FEAT * POLY_K
#define POOLSZ 4
#define NPOOL 2500
#define NSL 16                 // column slices (slice-contiguous layout)

typedef short bf16x8 __attribute__((ext_vector_type(8)));
typedef unsigned short u16x8 __attribute__((ext_vector_type(8)));
typedef unsigned int u32x4 __attribute__((ext_vector_type(4)));
typedef float f32x4 __attribute__((ext_vector_type(4)));
typedef float f32x2 __attribute__((ext_vector_type(2)));

__device__ __forceinline__ unsigned short f2bf(float f) {
  unsigned int u = __float_as_uint(f);
  unsigned int r = u + 0x7FFFu + ((u >> 16) & 1u);   // RNE
  return (unsigned short)(r >> 16);
}
__device__ __forceinline__ float bf2f(unsigned short u) {
  return __uint_as_float(((unsigned int)u) << 16);
}
// unpack one dword (2 packed bf16) to float2 {lo, hi} — 2 VALU ops
__device__ __forceinline__ f32x2 unpk(unsigned int u) {
  f32x2 r;
  r[0] = __uint_as_float(u << 16);
  r[1] = __uint_as_float(u & 0xFFFF0000u);
  return r;
}

// ---------------- CSR build ----------------

__global__ void zero_int_kernel(int* __restrict__ p, int n) {
  int i = blockIdx.x * 256 + threadIdx.x;
  if (i < n) p[i] = 0;
}

__global__ void hist_kernel(const int* __restrict__ rows, int* __restrict__ deg) {
  int e = blockIdx.x * 256 + threadIdx.x;
  if (e < N_EDGES) atomicAdd(&deg[rows[e]], 1);
}

// wave-shuffle scan: 16 waves x 64 lanes, 4 barriers/chunk
__global__ void scan_kernel(const int* __restrict__ deg, int* __restrict__ row_start,
                            int* __restrict__ cursor) {
  __shared__ int wsum[16];
  __shared__ int carry_sm;
  int t = threadIdx.x;
  int lane = t & 63, wid = t >> 6;
  if (t == 0) { carry_sm = 0; row_start[0] = 0; }
  __syncthreads();
  for (int base = 0; base < N_NODES; base += 1024) {
    int idx = base + t;
    int v = (idx < N_NODES) ? deg[idx] : 0;
    int x = v;
    #pragma unroll
    for (int off = 1; off < 64; off <<= 1) {
      int y = __shfl_up(x, off, 64);
      if (lane >= off) x += y;
    }
    if (lane == 63) wsum[wid] = x;
    __syncthreads();
    if (wid == 0) {
      int sv = (lane < 16) ? wsum[lane] : 0;
      #pragma unroll
      for (int off = 1; off < 16; off <<= 1) {
        int y = __shfl_up(sv, off, 64);
        if (lane >= off) sv += y;
      }
      if (lane < 16) wsum[lane] = sv;
    }
    __syncthreads();
    int incl = x + (wid > 0 ? wsum[wid - 1] : 0) + carry_sm;
    if (idx < N_NODES) {
      row_start[idx + 1] = incl;
      cursor[idx] = incl - v;
    }
    __syncthreads();                 // all carry reads done
    if (t == 1023) carry_sm = incl;  // wid=15,lane=63 -> chunk total (incl carry)
    __syncthreads();
  }
}

// scatter into interleaved {col, val_bits} pairs: one 8-B load per edge in spmm
__global__ void scatter_kernel(const int* __restrict__ rows, const int* __restrict__ cols,
                               const float* __restrict__ vals, int* __restrict__ cursor,
                               int2* __restrict__ csr_pairs) {
  int e = blockIdx.x * 256 + threadIdx.x;
  if (e < N_EDGES) {
    int r = rows[e];
    int p = atomicAdd(&cursor[r], 1);
    csr_pairs[p] = make_int2(cols[e], __float_as_int(vals[e]));
  }
}

// ---------------- within-chunk degree sort (chunk = 16 rows) ----------------
// Waves co-schedule 4 rows in lockstep: trip count = max(deg of 4). Sorting rows WITHIN each
// 16-row chunk puts similar degrees in the same wave (trip ~ mean), while keeping the
// permutation inside a 16-row window -> csr/prev/xout locality intact.

__global__ void bsort_kernel(const int* __restrict__ deg, int* __restrict__ perm) {
  int chunk = blockIdx.x * 256 + threadIdx.x;     // 625 chunks of 16 rows
  if (chunk >= (N_NODES + 15) / 16) return;
  int base = chunk * 16;
  int idx[16], dg[16];
  #pragma unroll
  for (int j = 0; j < 16; ++j) {
    int r = base + j;
    idx[j] = r;
    dg[j] = (r < N_NODES) ? deg[r] : 0x7fffffff;
  }
  #pragma unroll
  for (int a = 1; a < 16; ++a) {          // insertion sort ascending by degree
    int dv = dg[a], iv = idx[a];
    int b = a - 1;
    while (b >= 0 && dg[b] > dv) { dg[b + 1] = dg[b]; idx[b + 1] = idx[b]; --b; }
    dg[b + 1] = dv; idx[b + 1] = iv;
  }
  #pragma unroll
  for (int j = 0; j < 16; ++j)
    if (base + j < N_NODES) perm[base + j] = idx[j];
}

// ---------------- weight prepack: B-fragment lane order, k' = kpoly*64+f ----------------

__global__ void wpack_kernel(const float* __restrict__ weight, unsigned short* __restrict__ wpack) {
  int id = blockIdx.x * 256 + threadIdx.x;      // 8*10*64 = 5120 lane-slots
  if (id >= 5120) return;
  int ft = id / 640;
  int c = (id / 64) % 10;
  int l = id % 64;
  int fo = ft * 16 + (l & 15);
  unsigned short v[8];
  #pragma unroll
  for (int j = 0; j < 8; ++j) {
    int k = c * 32 + ((l >> 4)) * 8 + j;
    int row = (k & 63) * POLY_K + (k >> 6);
    v[j] = f2bf(weight[row * OUT_FEAT + fo]);
  }
  ushort4* dst = (ushort4*)&wpack[(size_t)id * 8];
  dst[0] = make_ushort4(v[0], v[1], v[2], v[3]);
  dst[1] = make_ushort4(v[4], v[5], v[6], v[7]);
}

// ---------------- transpose into slice-contiguous layout (node-blocked) ----------------
// 8 nodes/block: per wave (fixed b) reads 8 adjacent nodes x 64 feats = 2 KB CONTIGUOUS.

template <int BB>
__global__ __launch_bounds__(256) void transpose_kernel(const float* __restrict__ x,
                                                        unsigned short* __restrict__ t0, int b0) {
  constexpr int CB = 64 * BB;
  constexpr int SCOLS = CB / NSL;
  constexpr size_t SLICE_SL = (size_t)N_NODES * SCOLS;
  constexpr int NN = 8;                     // nodes per block (grid 1250)
  int n0 = blockIdx.x * NN;
  int t = threadIdx.x;
  int bsub = t >> 6;                        // 0..3
  int n = (t >> 3) & 7;                     // 0..7
  int f8 = t & 7;                           // 0..7 (8 floats each)
  int node = n0 + n;
  #pragma unroll
  for (int bi = 0; bi < BB / 4; ++bi) {
    int b = bi * 4 + bsub;
    const float* xp = &x[((size_t)(b0 + b) * N_NODES + node) * IN_FEAT + f8 * 8];
    float4 v0 = *(const float4*)xp;
    float4 v1 = *(const float4*)(xp + 4);
    u16x8 o;
    o[0] = f2bf(v0.x); o[1] = f2bf(v0.y); o[2] = f2bf(v0.z); o[3] = f2bf(v0.w);
    o[4] = f2bf(v1.x); o[5] = f2bf(v1.y); o[6] = f2bf(v1.z); o[7] = f2bf(v1.w);
    int i = b * 64 + f8 * 8;
    int sl = i / SCOLS;
    int cw = i - sl * SCOLS;
    *(u16x8*)&t0[(size_t)sl * SLICE_SL + (size_t)node * SCOLS + cw] = o;
  }
}

// ---------------- SpMM (bf16): slice-contiguous, pair-CSR, within-chunk sorted rows ----------
// Round-8 form (best measured): 4 rows/wave, 16 lanes x dwordx4 per gather = 1 KB/instr
// serving 4 edges. R11 lesson: never shrink per-lane load width — gather instruction
// count, not TLP, is the binding rate on the L1/TA path.

template <int BB>
__global__ __launch_bounds__(256) void spmm_kernel(const unsigned short* __restrict__ xin,
                                                   const unsigned short* __restrict__ prev,
                                                   unsigned short* __restrict__ xout,
                                                   const int* __restrict__ row_start,
                                                   const int2* __restrict__ csr_pairs,
                                                   const int* __restrict__ perm,
                                                   float alpha, int use_prev) {
  constexpr int CB = 64 * BB;
  constexpr int SCOLS = CB / NSL;       // cols per slice
  constexpr size_t SLICE_SL = (size_t)N_NODES * SCOLS;
  constexpr int LPR = SCOLS / 8;        // lanes per row-slice (8 bf16 each)
  constexpr int RPB = 256 / LPR;        // rows per block
  constexpr int RB = (N_NODES + RPB - 1) / RPB;
  constexpr int PHB = RB * 8;           // blocks per phase
  int bid = blockIdx.x;
  int phase = bid / PHB;
  int rem = bid - phase * PHB;
  int xcd = rem & 7;
  int rowblk = rem >> 3;
  int slice = phase * 8 + xcd;
  int t = threadIdx.x;
  int rl = t / LPR;
  int cl = t - rl * LPR;
  int si = rowblk * RPB + rl;
  if (si >= N_NODES) return;
  int n = perm[si];
  unsigned off = (unsigned)cl * 8u;

  const unsigned short* xs = xin  + (size_t)slice * SLICE_SL;
  const unsigned short* ps = prev + (size_t)slice * SLICE_SL;
  unsigned short*       os = xout + (size_t)slice * SLICE_SL;

  int s = row_start[n];
  int e = row_start[n + 1];
  f32x2 a0 = {0.f, 0.f}, a1 = {0.f, 0.f}, a2 = {0.f, 0.f}, a3 = {0.f, 0.f};

  int i = s;
  for (; i + 7 < e; i += 8) {
    int2 E[8];
    #pragma unroll
    for (int u = 0; u < 8; ++u) E[u] = csr_pairs[i + u];
    u32x4 d[8];
    #pragma unroll
    for (int u = 0; u < 8; ++u) d[u] = *(const u32x4*)&xs[(unsigned)E[u].x * SCOLS + off];
    #pragma unroll
    for (int u = 0; u < 8; ++u) {
      float vv = __int_as_float(E[u].y);
      f32x2 w = {vv, vv};
      a0 = __builtin_elementwise_fma(w, unpk(d[u][0]), a0);
      a1 = __builtin_elementwise_fma(w, unpk(d[u][1]), a1);
      a2 = __builtin_elementwise_fma(w, unpk(d[u][2]), a2);
      a3 = __builtin_elementwise_fma(w, unpk(d[u][3]), a3);
    }
  }
  for (; i + 3 < e; i += 4) {
    int2 E[4];
    #pragma unroll
    for (int u = 0; u < 4; ++u) E[u] = csr_pairs[i + u];
    u32x4 d[4];
    #pragma unroll
    for (int u = 0; u < 4; ++u) d[u] = *(const u32x4*)&xs[(unsigned)E[u].x * SCOLS + off];
    #pragma unroll
    for (int u = 0; u < 4; ++u) {
      float vv = __int_as_float(E[u].y);
      f32x2 w = {vv, vv};
      a0 = __builtin_elementwise_fma(w, unpk(d[u][0]), a0);
      a1 = __builtin_elementwise_fma(w, unpk(d[u][1]), a1);
      a2 = __builtin_elementwise_fma(w, unpk(d[u][2]), a2);
      a3 = __builtin_elementwise_fma(w, unpk(d[u][3]), a3);
    }
  }
  for (; i < e; ++i) {
    int2 E0 = csr_pairs[i];
    u32x4 d0 = *(const u32x4*)&xs[(unsigned)E0.x * SCOLS + off];
    float vv = __int_as_float(E0.y);
    f32x2 w0 = {vv, vv};
    a0 = __builtin_elementwise_fma(w0, unpk(d0[0]), a0);
    a1 = __builtin_elementwise_fma(w0, unpk(d0[1]), a1);
    a2 = __builtin_elementwise_fma(w0, unpk(d0[2]), a2);
    a3 = __builtin_elementwise_fma(w0, unpk(d0[3]), a3);
  }

  unsigned nelt = (unsigned)n * SCOLS + off;
  u16x8 o;
  if (use_prev) {
    u32x4 qd = *(const u32x4*)&ps[nelt];
    f32x2 q0 = unpk(qd[0]), q1 = unpk(qd[1]), q2 = unpk(qd[2]), q3 = unpk(qd[3]);
    o[0] = f2bf(alpha * a0[0] - q0[0]); o[1] = f2bf(alpha * a0[1] - q0[1]);
    o[2] = f2bf(alpha * a1[0] - q1[0]); o[3] = f2bf(alpha * a1[1] - q1[1]);
    o[4] = f2bf(alpha * a2[0] - q2[0]); o[5] = f2bf(alpha * a2[1] - q2[1]);
    o[6] = f2bf(alpha * a3[0] - q3[0]); o[7] = f2bf(alpha * a3[1] - q3[1]);
  } else {
    o[0] = f2bf(alpha * a0[0]); o[1] = f2bf(alpha * a0[1]);
    o[2] = f2bf(alpha * a1[0]); o[3] = f2bf(alpha * a1[1]);
    o[4] = f2bf(alpha * a2[0]); o[5] = f2bf(alpha * a2[1]);
    o[6] = f2bf(alpha * a3[0]); o[7] = f2bf(alpha * a3[1]);
  }
  *(u16x8*)&os[nelt] = o;
}

// ---------------- MFMA GEMM + bias + ReLU + maxpool(4), 2-phase pipelined staging ----------
// Round-8 config (MB=16, 40960 B LDS, 4 blocks/CU): best-measured total. Phase-1: stage
// kpoly 0-1; barrier; ISSUE stage kpoly 2-4, compute c=0..3 with PRE-LOADED B-fragments
// (pure LDS+MFMA, no VMEM consume); barrier; compute c=4..9.

template <int BB>
__global__ __launch_bounds__(256, 4) void gemm_mfma_kernel(const unsigned short* __restrict__ slices,
                                                           const unsigned short* __restrict__ wpack,
                                                           const float* __restrict__ bias,
                                                           float* __restrict__ out, int b0) {
  constexpr int CB = 64 * BB;
  constexpr int SCOLS = CB / NSL;
  constexpr size_t SLICE_SL = (size_t)N_NODES * SCOLS;
  constexpr int MB = (BB >= 16) ? 16 : BB;        // b's per block
  constexpr int MT = MB / 4;                      // 16-row M-tiles
  constexpr int SPAN = MB * 64;                   // cols per block
  constexpr int ROWS = 4 * MB;                    // A rows (bloc*4 + nd)
  constexpr int CHUNKS = ROWS * 40;               // 16B chunks total
  __shared__ unsigned short A[POLY_K * ROWS * 64]; // K-major: [kpoly][row][64]

  int g = blockIdx.x;
  int bh = blockIdx.y;
  int t = threadIdx.x;

  auto stage = [&](int idx0) {
    int idx = idx0 + t;
    int kpoly = idx / (ROWS * 8);
    int rem = idx - kpoly * (ROWS * 8);
    int row = rem >> 3;
    int cphys = idx & 7;
    int clog3 = cphys ^ (row & 7);                // swizzle within kpoly's 8-chunk group
    int fb = clog3 * 8;
    int bloc = row >> 2;
    int nd = row & 3;
    int c = bh * SPAN + bloc * 64 + fb;           // global column in [0, CB)
    int sl = c / SCOLS;
    int cw = c & (SCOLS - 1);
    const unsigned short* gsrc = &slices[((size_t)kpoly * NSL + sl) * SLICE_SL +
                                         (size_t)(g * POOLSZ + nd) * SCOLS + cw];
    unsigned short* lbase = &A[(size_t)(idx0 + (t & 192)) * 8];   // wave-uniform base
    __builtin_amdgcn_global_load_lds((const __attribute__((address_space(1))) unsigned int*)gsrc,
                                     (__attribute__((address_space(3))) unsigned int*)lbase,
                                     16, 0, 0);
  };

  int w = t >> 6;          // wave 0..3: fo-tiles {2w, 2w+1}
  int l = t & 63;
  int lm = l & 15;
  int q = l >> 4;
  int swz = lm & 7;

  f32x4 acc[MT][2];
  #pragma unroll
  for (int mt = 0; mt < MT; ++mt)
    #pragma unroll
    for (int fj = 0; fj < 2; ++fj) {
      acc[mt][fj][0] = 0.f; acc[mt][fj][1] = 0.f;
      acc[mt][fj][2] = 0.f; acc[mt][fj][3] = 0.f;
    }

  if constexpr (MB == 16) {
    constexpr int PH1 = 2 * ROWS * 8;             // kpoly 0,1 = 1024 chunks = 4 iters
    for (int idx0 = 0; idx0 < PH1; idx0 += 256) stage(idx0);
    // preload B-fragments for c=0..3 (resident after the barrier drain; 32 VGPR)
    bf16x8 bpre[4][2];
    #pragma unroll
    for (int c = 0; c < 4; ++c)
      #pragma unroll
      for (int fj = 0; fj < 2; ++fj)
        bpre[c][fj] = *(const bf16x8*)&wpack[(size_t)((((w * 2 + fj) * 10) + c) * 64 + l) * 8];
    __syncthreads();                              // kpoly 0,1 + bpre resident
    for (int idx0 = PH1; idx0 < CHUNKS; idx0 += 256) stage(idx0);  // kpoly 2..4 in flight
    #pragma unroll
    for (int c = 0; c < 4; ++c) {                 // kpoly 0,1 — pure LDS+MFMA
      #pragma unroll
      for (int mt = 0; mt < MT; ++mt) {
        bf16x8 afrag = *(const bf16x8*)
            &A[((c >> 1) * ROWS + mt * 16 + lm) * 64 + ((((c & 1) * 4 + q) ^ swz) << 3)];
        acc[mt][0] = __builtin_amdgcn_mfma_f32_16x16x32_bf16(afrag, bpre[c][0], acc[mt][0], 0, 0, 0);
        acc[mt][1] = __builtin_amdgcn_mfma_f32_16x16x32_bf16(afrag, bpre[c][1], acc[mt][1], 0, 0, 0);
      }
    }
    __syncthreads();                              // kpoly 2..4 resident
    #pragma unroll
    for (int c = 4; c < 10; ++c) {
      bf16x8 bfrag[2];
      #pragma unroll
      for (int fj = 0; fj < 2; ++fj)
        bfrag[fj] = *(const bf16x8*)&wpack[(size_t)((((w * 2 + fj) * 10) + c) * 64 + l) * 8];
      #pragma unroll
      for (int mt = 0; mt < MT; ++mt) {
        bf16x8 afrag = *(const bf16x8*)
            &A[((c >> 1) * ROWS + mt * 16 + lm) * 64 + ((((c & 1) * 4 + q) ^ swz) << 3)];
        acc[mt][0] = __builtin_amdgcn_mfma_f32_16x16x32_bf16(afrag, bfrag[0], acc[mt][0], 0, 0, 0);
        acc[mt][1] = __builtin_amdgcn_mfma_f32_16x16x32_bf16(afrag, bfrag[1], acc[mt][1], 0, 0, 0);
      }
    }
  } else {
    for (int idx0 = 0; idx0 < CHUNKS; idx0 += 256) stage(idx0);
    __syncthreads();
    #pragma unroll
    for (int c = 0; c < 10; ++c) {
      bf16x8 bfrag[2];
      #pragma unroll
      for (int fj = 0; fj < 2; ++fj)
        bfrag[fj] = *(const bf16x8*)&wpack[(size_t)((((w * 2 + fj) * 10) + c) * 64 + l) * 8];
      #pragma unroll
      for (int mt = 0; mt < MT; ++mt) {
        bf16x8 afrag = *(const bf16x8*)
            &A[((c >> 1) * ROWS + mt * 16 + lm) * 64 + ((((c & 1) * 4 + q) ^ swz) << 3)];
        acc[mt][0] = __builtin_amdgcn_mfma_f32_16x16x32_bf16(afrag, bfrag[0], acc[mt][0], 0, 0, 0);
        acc[mt][1] = __builtin_amdgcn_mfma_f32_16x16x32_bf16(afrag, bfrag[1], acc[mt][1], 0, 0, 0);
      }
    }
  }

  #pragma unroll
  for (int fj = 0; fj < 2; ++fj) {
    int fo = (w * 2 + fj) * 16 + lm;
    float bv = bias[fo];
    #pragma unroll
    for (int mt = 0; mt < MT; ++mt) {
      float mx = fmaxf(fmaxf(acc[mt][fj][0], acc[mt][fj][1]),
                       fmaxf(acc[mt][fj][2], acc[mt][fj][3]));
      float val = fmaxf(mx + bv, 0.f);
      int b = b0 + bh * MB + mt * 4 + q;
      out[((size_t)b * NPOOL + g) * OUT_FEAT + fo] = val;
    }
  }
}

// ---------------- pipeline ----------------

template <int BB>
static void run_pipeline(const float* x, const float* bias,
                         const int* row_start, const int2* csr_pairs, const int* perm,
                         const unsigned short* wpack,
                         unsigned short* slices, float* out, hipStream_t stream) {
  constexpr int CB = 64 * BB;
  constexpr size_t TERM = (size_t)N_NODES * CB;   // elements per k-term (NSL slices)
  constexpr int LPR = (CB / NSL) / 8;
  constexpr int RPB = 256 / LPR;
  constexpr int NBLK = ((N_NODES + RPB - 1) / RPB) * NSL;
  constexpr int MB = (BB >= 16) ? 16 : BB;
  for (int b0 = 0; b0 < BATCH; b0 += BB) {
    transpose_kernel<BB><<<N_NODES / 8, 256, 0, stream>>>(x, slices, b0);
    for (int k = 1; k < POLY_K; ++k) {
      const unsigned short* xin  = slices + (size_t)(k - 1) * TERM;
      const unsigned short* prev = (k >= 2) ? slices + (size_t)(k - 2) * TERM : slices;
      unsigned short* xout = slices + (size_t)k * TERM;
      float alpha = (k == 1) ? 1.0f : 2.0f;
      spmm_kernel<BB><<<NBLK, 256, 0, stream>>>(xin, prev, xout, row_start,
                                                csr_pairs, perm, alpha,
                                                (k >= 2) ? 1 : 0);
    }
    gemm_mfma_kernel<BB><<<dim3(NPOOL, BB / MB), 256, 0, stream>>>(slices, wpack, bias, out, b0);
  }
}

static size_t needed_bytes(int BB) {
  return 1522176u + (size_t)6400000 * BB;   // deg/cursor/row_start/perm + pairs + wpack + slices
}

extern "C" void kernel_launch(void* const* d_in, const int* in_sizes, int n_in,
                              void* d_out, int out_size, void* d_ws, size_t ws_size,
                              hipStream_t stream) {
  const float* x        = (const float*)d_in[0];
  const int*   lap_rows = (const int*)d_in[1];
  const int*   lap_cols = (const int*)d_in[2];
  const float* lap_vals = (const float*)d_in[3];
  const float* weight   = (const float*)d_in[4];
  const float* bias     = (const float*)d_in[5];
  float* out = (float*)d_out;

  int* deg       = (int*)d_ws;
  int* cursor    = deg + 10016;
  int* row_start = cursor + 10016;
  int* perm      = row_start + 10016;
  int2* csr_pairs = (int2*)(perm + 10016);
  unsigned short* wpack = (unsigned short*)(csr_pairs + N_EDGES);  // 40960 ushorts
  unsigned short* slices = wpack + 40960;                          // bf16 terms

  int BB = 0;
  if      (ws_size >= needed_bytes(32)) BB = 32;
  else if (ws_size >= needed_bytes(16)) BB = 16;
  else if (ws_size >= needed_bytes(8))  BB = 8;
  else if (ws_size >= needed_bytes(4))  BB = 4;
  if (BB == 0) return;

  zero_int_kernel<<<(N_NODES + 255) / 256, 256, 0, stream>>>(deg, N_NODES);
  hist_kernel<<<(N_EDGES + 255) / 256, 256, 0, stream>>>(lap_rows, deg);
  scan_kernel<<<1, 1024, 0, stream>>>(deg, row_start, cursor);
  scatter_kernel<<<(N_EDGES + 255) / 256, 256, 0, stream>>>(lap_rows, lap_cols, lap_vals,
                                                            cursor, csr_pairs);
  bsort_kernel<<<3, 256, 0, stream>>>(deg, perm);
  wpack_kernel<<<20, 256, 0, stream>>>(weight, wpack);

  switch (BB) {
    case 32: run_pipeline<32>(x, bias, row_start, csr_pairs, perm, wpack, slices, out, stream); break;
    case 16: run_pipeline<16>(x, bias, row_start, csr_pairs, perm, wpack, slices, out, stream); break;
    case 8:  run_pipeline<8>(x, bias, row_start, csr_pairs, perm, wpack, slices, out, stream); break;
    case 4:  run_pipeline<4>(x, bias, row_start, csr_pairs, perm, wpack, slices, out, stream); break;
  }
}